// Round 9
// baseline (150.098 us; speedup 1.0000x reference)
//
#include <hip/hip_runtime.h>
#include <hip/hip_fp16.h>

struct alignas(8) Half4 { __half2 lo; __half2 hi; };

#define MAXDEG 64     // dst-degree ~ Poisson(17); observed max ~45. Guarded both sides.
#define XS_STRIDE 33  // float4 units; pad kills bank conflicts
#define EPB 2048      // edges per partition block

// ---------------- CSR build, pass 1: bucket histogram (bucket = dst >> 7) ----------------

__global__ void __launch_bounds__(256) k_hist(
    const int* __restrict__ ei, int E, int N, int* __restrict__ ghist) {
  __shared__ int lh[400];
  int t = threadIdx.x;
  int Et = E + N;
  for (int j = t; j < 400; j += 256) lh[j] = 0;
  __syncthreads();
  int ebase = blockIdx.x * EPB;
  #pragma unroll
  for (int i = 0; i < 8; ++i) {
    int e = ebase + i * 256 + t;
    if (e < Et) {
      int d = (e < E) ? ei[E + e] : (e - E);
      atomicAdd(&lh[d >> 7], 1);
    }
  }
  __syncthreads();
  int nb = (N + 127) >> 7;
  for (int j = t; j < nb; j += 256)
    if (lh[j]) atomicAdd(&ghist[j], lh[j]);
}

// ---------------- pass 2: exclusive scan of 391 bucket counts (1 block) ----------------

__global__ void __launch_bounds__(512) k_scan(
    const int* __restrict__ ghist, int* __restrict__ bo, int* __restrict__ bc, int nb) {
  __shared__ int sh[512];
  int t = threadIdx.x;
  int v = (t < nb) ? ghist[t] : 0;
  sh[t] = v;
  __syncthreads();
  for (int off = 1; off < 512; off <<= 1) {
    int u = (t >= off) ? sh[t - off] : 0;
    __syncthreads();
    sh[t] += u;
    __syncthreads();
  }
  if (t < nb) {
    int excl = sh[t] - v;
    bo[t] = excl;
    bc[t] = excl;
  }
  if (t == nb - 1) bo[nb] = sh[t];
}

// ---------------- pass 3 (fused || GEMM1): partition edges into bucket-ordered COO ----------------
// blocks [0,gb): gemm1.  blocks [gb,gb+pb): partition EPB edges each via LDS ranks
// (one global atomic per (block,bucket) -> ~160k atomics, writes advance 391
// sequential cursors -> near-full-line write efficiency).

__global__ void __launch_bounds__(256) k_partg(
    const int* __restrict__ ei, int E, int N, int gb,
    int* __restrict__ bc, unsigned int* __restrict__ coo,
    const float* __restrict__ x, const float* __restrict__ W,
    const float* __restrict__ as, const float* __restrict__ ad,
    __half* __restrict__ h1h, float* __restrict__ als, float* __restrict__ ald) {
  __shared__ float4 xs[64 * XS_STRIDE];
  int b = blockIdx.x;
  int t = threadIdx.x;

  if (b >= gb) {                       // ---- partition branch ----
    int* cnt = (int*)xs;               // [400]
    int* bas = cnt + 400;              // [400]
    int Et = E + N;
    int ebase = (b - gb) * EPB;
    for (int j = t; j < 400; j += 256) cnt[j] = 0;
    __syncthreads();
    int b8[8], r8[8]; unsigned int pk[8];
    #pragma unroll
    for (int i = 0; i < 8; ++i) {
      int e = ebase + i * 256 + t;
      b8[i] = -1;
      if (e < Et) {
        int s, d;
        if (e < E) { s = ei[e]; d = ei[E + e]; } else { s = d = e - E; }
        int bk = d >> 7;
        b8[i] = bk;
        pk[i] = (unsigned int)s | ((unsigned int)(d & 127) << 16);
        r8[i] = atomicAdd(&cnt[bk], 1);
      }
    }
    __syncthreads();
    int nb = (N + 127) >> 7;
    for (int j = t; j < nb; j += 256) {
      int c = cnt[j];
      bas[j] = c ? atomicAdd(&bc[j], c) : 0;
    }
    __syncthreads();
    #pragma unroll
    for (int i = 0; i < 8; ++i)
      if (b8[i] >= 0) coo[bas[b8[i]] + r8[i]] = pk[i];
    return;
  }

  // ---- gemm1 branch ----
  int base = b * 64;
  const float4* x4 = (const float4*)x;
  #pragma unroll
  for (int i = 0; i < 8; ++i) {
    int idx = t + i * 256;
    int n = idx >> 5, k4 = idx & 31;
    int gn = base + n; if (gn >= N) gn = N - 1;
    xs[n * XS_STRIDE + k4] = x4[gn * 32 + k4];
  }
  __syncthreads();

  int c4 = t & 31, nr = t >> 5;
  const float4* w4 = (const float4*)W;
  float4 acc[8];
  #pragma unroll
  for (int i = 0; i < 8; ++i) acc[i] = make_float4(0.f, 0.f, 0.f, 0.f);

  for (int k4 = 0; k4 < 32; ++k4) {
    float4 w0 = w4[(k4 * 4 + 0) * 32 + c4];
    float4 w1 = w4[(k4 * 4 + 1) * 32 + c4];
    float4 w2 = w4[(k4 * 4 + 2) * 32 + c4];
    float4 w3 = w4[(k4 * 4 + 3) * 32 + c4];
    #pragma unroll
    for (int i = 0; i < 8; ++i) {
      float4 xv = xs[(nr * 8 + i) * XS_STRIDE + k4];
      acc[i].x += xv.x * w0.x + xv.y * w1.x + xv.z * w2.x + xv.w * w3.x;
      acc[i].y += xv.x * w0.y + xv.y * w1.y + xv.z * w2.y + xv.w * w3.y;
      acc[i].z += xv.x * w0.z + xv.y * w1.z + xv.z * w2.z + xv.w * w3.z;
      acc[i].w += xv.x * w0.w + xv.y * w1.w + xv.z * w2.w + xv.w * w3.w;
    }
  }

  int hh = c4 >> 3;
  int cl = (c4 & 7) * 4;
  float a10 = as[hh * 32 + cl], a11 = as[hh * 32 + cl + 1],
        a12 = as[hh * 32 + cl + 2], a13 = as[hh * 32 + cl + 3];
  float a20 = ad[hh * 32 + cl], a21 = ad[hh * 32 + cl + 1],
        a22 = ad[hh * 32 + cl + 2], a23 = ad[hh * 32 + cl + 3];
  Half4* h1p = (Half4*)h1h;
  #pragma unroll
  for (int i = 0; i < 8; ++i) {
    int gn = base + nr * 8 + i;
    float ps = acc[i].x * a10 + acc[i].y * a11 + acc[i].z * a12 + acc[i].w * a13;
    float pd = acc[i].x * a20 + acc[i].y * a21 + acc[i].z * a22 + acc[i].w * a23;
    ps += __shfl_xor(ps, 1); pd += __shfl_xor(pd, 1);
    ps += __shfl_xor(ps, 2); pd += __shfl_xor(pd, 2);
    ps += __shfl_xor(ps, 4); pd += __shfl_xor(pd, 4);
    if (gn < N) {
      Half4 hv;
      hv.lo = __floats2half2_rn(acc[i].x, acc[i].y);
      hv.hi = __floats2half2_rn(acc[i].z, acc[i].w);
      h1p[gn * 32 + c4] = hv;
      if ((c4 & 7) == 0) { als[gn * 4 + hh] = ps; ald[gn * 4 + hh] = pd; }
    }
  }
}

// ---------------- pass 4: per-bucket adj tile build in LDS, coalesced writeout ----------------
// One block per bucket (128 nodes). LDS atomics for slots; 16 KB coalesced store.

__global__ void __launch_bounds__(256) k_bfill(
    const unsigned int* __restrict__ coo, const int* __restrict__ bo,
    unsigned short* __restrict__ adj, int* __restrict__ cursor, int N) {
  __shared__ unsigned short tile[128 * MAXDEG];   // 16 KB
  __shared__ int lcur[128];
  int bk = blockIdx.x;
  int t = threadIdx.x;
  int nb0 = bk << 7;
  int beg = bo[bk], end = bo[bk + 1];
  for (int j = t; j < 128; j += 256) lcur[j] = 0;
  __syncthreads();
  for (int e = beg + t; e < end; e += 256) {
    unsigned int u = coo[e];
    int dlow = u >> 16;
    int slot = atomicAdd(&lcur[dlow], 1);
    if (slot < MAXDEG) tile[(dlow << 6) + slot] = (unsigned short)(u & 0xFFFF);
  }
  __syncthreads();
  uint4* dst = (uint4*)(adj + (size_t)nb0 * MAXDEG);
  const uint4* src = (const uint4*)tile;
  for (int j = t; j < 1024; j += 256)                 // 8 uint4 per node row
    if (nb0 + (j >> 3) < N) dst[j] = src[j];
  for (int j = t; j < 128; j += 256)
    if (nb0 + j < N) cursor[nb0 + j] = lcur[j];
}

// ---------------- GEMM 2: h2 = h2in(fp16) @ W2, h2 -> fp16 ----------------

__global__ void __launch_bounds__(256) k_gemm2(
    const __half* __restrict__ hin, const float* __restrict__ W,
    const float* __restrict__ as, const float* __restrict__ ad,
    __half* __restrict__ h2h, float* __restrict__ als,
    float* __restrict__ ald, int N) {
  __shared__ float4 xs[64 * XS_STRIDE];   // 33792 B
  __shared__ float2 ws[128 * 16];         // 16384 B : W2 as float2 [128 k][16 colpairs]
  int t = threadIdx.x;
  int base = blockIdx.x * 64;
  const uint2* xg = (const uint2*)hin;
  #pragma unroll
  for (int i = 0; i < 8; ++i) {
    int idx = t + i * 256;
    int n = idx >> 5, k4 = idx & 31;
    int gn = base + n; if (gn >= N) gn = N - 1;
    uint2 u = xg[gn * 32 + k4];
    __half2 a = *(const __half2*)&u.x;
    __half2 b = *(const __half2*)&u.y;
    float2 fa = __half22float2(a), fb = __half22float2(b);
    xs[n * XS_STRIDE + k4] = make_float4(fa.x, fa.y, fb.x, fb.y);
  }
  const float2* w2g = (const float2*)W;
  #pragma unroll
  for (int i = 0; i < 8; ++i) ws[t + i * 256] = w2g[t + i * 256];
  __syncthreads();

  int c2 = t & 15, nr = t >> 4;
  float2 acc[4];
  #pragma unroll
  for (int i = 0; i < 4; ++i) acc[i] = make_float2(0.f, 0.f);

  #pragma unroll 4
  for (int k4 = 0; k4 < 32; ++k4) {
    float2 w0 = ws[(k4 * 4 + 0) * 16 + c2];
    float2 w1 = ws[(k4 * 4 + 1) * 16 + c2];
    float2 w2v = ws[(k4 * 4 + 2) * 16 + c2];
    float2 w3 = ws[(k4 * 4 + 3) * 16 + c2];
    #pragma unroll
    for (int i = 0; i < 4; ++i) {
      float4 xv = xs[(nr * 4 + i) * XS_STRIDE + k4];
      acc[i].x += xv.x * w0.x + xv.y * w1.x + xv.z * w2v.x + xv.w * w3.x;
      acc[i].y += xv.x * w0.y + xv.y * w1.y + xv.z * w2v.y + xv.w * w3.y;
    }
  }

  int hh = c2 >> 2;
  int cl = (c2 & 3) * 2;
  float a10 = as[hh * 8 + cl], a11 = as[hh * 8 + cl + 1];
  float a20 = ad[hh * 8 + cl], a21 = ad[hh * 8 + cl + 1];
  __half2* h2p = (__half2*)h2h;
  #pragma unroll
  for (int i = 0; i < 4; ++i) {
    int gn = base + nr * 4 + i;
    float ps = acc[i].x * a10 + acc[i].y * a11;
    float pd = acc[i].x * a20 + acc[i].y * a21;
    ps += __shfl_xor(ps, 1); pd += __shfl_xor(pd, 1);
    ps += __shfl_xor(ps, 2); pd += __shfl_xor(pd, 2);
    if (gn < N) {
      h2p[gn * 16 + c2] = __floats2half2_rn(acc[i].x, acc[i].y);
      if ((c2 & 3) == 0) { als[gn * 4 + hh] = ps; ald[gn * 4 + hh] = pd; }
    }
  }
}

// ---------------- Aggregation layer 1 (one wave per node, 128 cols, fp16 gather) ----------------

__global__ void k_agg1(const int* __restrict__ degp, const unsigned short* __restrict__ adj,
                       const __half* __restrict__ h1h, const float* __restrict__ als,
                       const float* __restrict__ ald, const float* __restrict__ bias,
                       __half* __restrict__ outh, int N) {
  int wid = (blockIdx.x * blockDim.x + threadIdx.x) >> 6;
  int lane = threadIdx.x & 63;
  if (wid >= N) return;
  int h = lane >> 4;
  int hb = h * 4;
  int jw = lane & 3, hw = (lane >> 2) & 3;
  float aldw = ald[wid * 4 + hw];
  float aldo = ald[wid * 4 + h];
  int deg = degp[wid]; if (deg > MAXDEG) deg = MAXDEG;
  const unsigned short* arow = adj + (size_t)wid * MAXDEG;
  float acc0 = 0.f, acc1 = 0.f, wsum = 0.f;
  const __half2* h1v = (const __half2*)h1h;
  int p = 0;
  for (; p + 3 < deg; p += 4) {
    int sj = arow[p + jw];
    int s0 = __shfl(sj, 0), s1 = __shfl(sj, 1), s2 = __shfl(sj, 2), s3 = __shfl(sj, 3);
    float2 v0 = __half22float2(h1v[s0 * 64 + lane]);
    float2 v1 = __half22float2(h1v[s1 * 64 + lane]);
    float2 v2 = __half22float2(h1v[s2 * 64 + lane]);
    float2 v3 = __half22float2(h1v[s3 * 64 + lane]);
    float ew = als[sj * 4 + hw] + aldw;
    ew = (ew > 0.f) ? ew : 0.2f * ew;
    float w = __expf(ew);
    float w0 = __shfl(w, hb + 0), w1 = __shfl(w, hb + 1),
          w2 = __shfl(w, hb + 2), w3 = __shfl(w, hb + 3);
    wsum += (w0 + w1) + (w2 + w3);
    acc0 += w0 * v0.x + w1 * v1.x + w2 * v2.x + w3 * v3.x;
    acc1 += w0 * v0.y + w1 * v1.y + w2 * v2.y + w3 * v3.y;
  }
  for (; p < deg; ++p) {
    int s0 = arow[p];
    float e0 = als[s0 * 4 + h] + aldo;
    e0 = (e0 > 0.f) ? e0 : 0.2f * e0;
    float w0 = __expf(e0);
    float2 v0 = __half22float2(h1v[s0 * 64 + lane]);
    wsum += w0;
    acc0 += w0 * v0.x;
    acc1 += w0 * v0.y;
  }
  float inv = 1.f / wsum;
  float o0 = fmaxf(acc0 * inv + bias[lane * 2 + 0], 0.f);
  float o1 = fmaxf(acc1 * inv + bias[lane * 2 + 1], 0.f);
  ((__half2*)outh)[wid * 64 + lane] = __floats2half2_rn(o0, o1);
}

// ---------------- Aggregation layer 2 + bias + log_softmax (32 lanes per node) ----------------

__global__ void k_agg2(const int* __restrict__ degp, const unsigned short* __restrict__ adj,
                       const __half* __restrict__ h2h, const float* __restrict__ als,
                       const float* __restrict__ ald, const float* __restrict__ bias,
                       float* __restrict__ out, int N) {
  int tid = blockIdx.x * blockDim.x + threadIdx.x;
  int node = tid >> 5;
  int sl = threadIdx.x & 31;
  if (node >= N) return;
  int h = sl >> 3;
  int hb = h * 4;
  int jw = sl & 3, hw = (sl >> 2) & 3;
  float aldw = ald[node * 4 + hw];
  float aldo = ald[node * 4 + h];
  int deg = degp[node]; if (deg > MAXDEG) deg = MAXDEG;
  const unsigned short* arow = adj + (size_t)node * MAXDEG;
  float acc = 0.f, wsum = 0.f;
  int p = 0;
  for (; p + 3 < deg; p += 4) {
    int sj = arow[p + jw];
    int s0 = __shfl(sj, 0, 32), s1 = __shfl(sj, 1, 32),
        s2 = __shfl(sj, 2, 32), s3 = __shfl(sj, 3, 32);
    float x0 = __half2float(h2h[s0 * 32 + sl]);
    float x1 = __half2float(h2h[s1 * 32 + sl]);
    float x2 = __half2float(h2h[s2 * 32 + sl]);
    float x3 = __half2float(h2h[s3 * 32 + sl]);
    float ew = als[sj * 4 + hw] + aldw;
    ew = (ew > 0.f) ? ew : 0.2f * ew;
    float w = __expf(ew);
    float w0 = __shfl(w, hb + 0, 32), w1 = __shfl(w, hb + 1, 32),
          w2 = __shfl(w, hb + 2, 32), w3 = __shfl(w, hb + 3, 32);
    wsum += (w0 + w1) + (w2 + w3);
    acc += (w0 * x0 + w1 * x1) + (w2 * x2 + w3 * x3);
  }
  for (; p < deg; ++p) {
    int s0 = arow[p];
    float e0 = als[s0 * 4 + h] + aldo;
    e0 = (e0 > 0.f) ? e0 : 0.2f * e0;
    float w0 = __expf(e0);
    wsum += w0;
    acc += w0 * __half2float(h2h[s0 * 32 + sl]);
  }
  float val = acc / wsum + bias[sl];
  float m = val;
  for (int off = 16; off; off >>= 1) m = fmaxf(m, __shfl_xor(m, off, 32));
  float ex = __expf(val - m);
  float ssum = ex;
  for (int off = 16; off; off >>= 1) ssum += __shfl_xor(ssum, off, 32);
  out[node * 32 + sl] = val - m - __logf(ssum);
}

// ---------------- launch ----------------

extern "C" void kernel_launch(void* const* d_in, const int* in_sizes, int n_in,
                              void* d_out, int out_size, void* d_ws, size_t ws_size,
                              hipStream_t stream) {
  const float* x   = (const float*)d_in[0];
  const int*   ei  = (const int*)d_in[1];
  const float* W1  = (const float*)d_in[2];
  const float* as1 = (const float*)d_in[3];
  const float* ad1 = (const float*)d_in[4];
  const float* b1  = (const float*)d_in[5];
  const float* W2  = (const float*)d_in[6];
  const float* as2 = (const float*)d_in[7];
  const float* ad2 = (const float*)d_in[8];
  const float* b2  = (const float*)d_in[9];
  float* outp = (float*)d_out;

  int N  = in_sizes[0] / 128;   // 50000
  int E  = in_sizes[1] / 2;     // 800000
  int Et = E + N;               // with self loops

  char* wsp = (char*)d_ws;
  size_t off = 0;
  auto alloc = [&](size_t bytes) -> void* {
    void* p = wsp + off;
    off += (bytes + 255) & ~(size_t)255;
    return p;
  };
  int*            ghist  = (int*)alloc(400 * 4);
  int*            bo     = (int*)alloc(400 * 4);
  int*            bc     = (int*)alloc(400 * 4);
  unsigned int*   coo    = (unsigned int*)alloc((size_t)Et * 4);
  int*            cursor = (int*)alloc((size_t)N * 4);
  unsigned short* adj    = (unsigned short*)alloc((size_t)N * MAXDEG * 2);
  __half*         h1     = (__half*)alloc((size_t)N * 128 * 2);
  float*          al1s   = (float*)alloc((size_t)N * 4 * 4);
  float*          al1d   = (float*)alloc((size_t)N * 4 * 4);
  __half*         h2in   = (__half*)alloc((size_t)N * 128 * 2);
  __half*         h2     = (__half*)alloc((size_t)N * 32 * 2);
  float*          al2s   = (float*)alloc((size_t)N * 4 * 4);
  float*          al2d   = (float*)alloc((size_t)N * 4 * 4);

  int nbuck = (N + 127) >> 7;            // 391
  int pb    = (Et + EPB - 1) / EPB;      // 416
  int gb    = (N + 63) / 64;             // 782

  hipMemsetAsync(ghist, 0, (size_t)nbuck * 4, stream);
  k_hist <<<pb, 256, 0, stream>>>(ei, E, N, ghist);
  k_scan <<<1, 512, 0, stream>>>(ghist, bo, bc, nbuck);
  k_partg<<<gb + pb, 256, 0, stream>>>(ei, E, N, gb, bc, coo,
                                       x, W1, as1, ad1, h1, al1s, al1d);
  k_bfill<<<nbuck, 256, 0, stream>>>(coo, bo, adj, cursor, N);

  k_agg1 <<<(N + 3) / 4, 256, 0, stream>>>(cursor, adj, h1, al1s, al1d, b1, h2in, N);
  k_gemm2<<<gb, 256, 0, stream>>>(h2in, W2, as2, ad2, h2, al2s, al2d, N);
  k_agg2 <<<(N + 7) / 8, 256, 0, stream>>>(cursor, adj, h2, al2s, al2d, b2, outp, N);
}

// Round 10
// 142.691 us; speedup vs baseline: 1.0519x; 1.0519x over previous
//
#include <hip/hip_runtime.h>
#include <hip/hip_fp16.h>

struct alignas(8) Half4 { __half2 lo; __half2 hi; };

#define MAXDEG 64     // dst-degree ~ Poisson(17); observed max ~45. Guarded both sides.
#define XS_STRIDE 33  // float4 units; pad kills bank conflicts

// ---------------- Fused: slotted-CSR fill (latency-bound) || GEMM1 (VALU-bound) ----------------
// blocks [0,gb): gemm1 on 64-node tile.  blocks [gb,gb+eb): edge scatter.
// r9 lesson: bucket-partition CSR build moves the cost into LDS atomics (no win);
// the simple scatter is write-transaction-bound at ~57us and hides gemm1 for free.

__global__ void __launch_bounds__(256) k_fg1(
    const int* __restrict__ ei, int E, int N, int gb,
    int* __restrict__ cursor, unsigned short* __restrict__ adj,
    const float* __restrict__ x, const float* __restrict__ W,
    const float* __restrict__ as, const float* __restrict__ ad,
    __half* __restrict__ h1h, float* __restrict__ als, float* __restrict__ ald) {
  __shared__ float4 xs[64 * XS_STRIDE];
  int b = blockIdx.x;
  int t = threadIdx.x;

  if (b >= gb) {                       // ---- fill branch ----
    int e = (b - gb) * 256 + t;
    int Et = E + N;
    if (e < Et) {
      int s, d;
      if (e < E) { s = ei[e]; d = ei[E + e]; } else { s = d = e - E; }
      int pos = atomicAdd(&cursor[d], 1);
      if (pos < MAXDEG) adj[(size_t)d * MAXDEG + pos] = (unsigned short)s;
    }
    return;
  }

  // ---- gemm1 branch ----
  int base = b * 64;
  const float4* x4 = (const float4*)x;
  #pragma unroll
  for (int i = 0; i < 8; ++i) {
    int idx = t + i * 256;
    int n = idx >> 5, k4 = idx & 31;
    int gn = base + n; if (gn >= N) gn = N - 1;
    xs[n * XS_STRIDE + k4] = x4[gn * 32 + k4];
  }
  __syncthreads();

  int c4 = t & 31, nr = t >> 5;
  const float4* w4 = (const float4*)W;
  float4 acc[8];
  #pragma unroll
  for (int i = 0; i < 8; ++i) acc[i] = make_float4(0.f, 0.f, 0.f, 0.f);

  for (int k4 = 0; k4 < 32; ++k4) {
    float4 w0 = w4[(k4 * 4 + 0) * 32 + c4];
    float4 w1 = w4[(k4 * 4 + 1) * 32 + c4];
    float4 w2 = w4[(k4 * 4 + 2) * 32 + c4];
    float4 w3 = w4[(k4 * 4 + 3) * 32 + c4];
    #pragma unroll
    for (int i = 0; i < 8; ++i) {
      float4 xv = xs[(nr * 8 + i) * XS_STRIDE + k4];
      acc[i].x += xv.x * w0.x + xv.y * w1.x + xv.z * w2.x + xv.w * w3.x;
      acc[i].y += xv.x * w0.y + xv.y * w1.y + xv.z * w2.y + xv.w * w3.y;
      acc[i].z += xv.x * w0.z + xv.y * w1.z + xv.z * w2.z + xv.w * w3.z;
      acc[i].w += xv.x * w0.w + xv.y * w1.w + xv.z * w2.w + xv.w * w3.w;
    }
  }

  int hh = c4 >> 3;
  int cl = (c4 & 7) * 4;
  float a10 = as[hh * 32 + cl], a11 = as[hh * 32 + cl + 1],
        a12 = as[hh * 32 + cl + 2], a13 = as[hh * 32 + cl + 3];
  float a20 = ad[hh * 32 + cl], a21 = ad[hh * 32 + cl + 1],
        a22 = ad[hh * 32 + cl + 2], a23 = ad[hh * 32 + cl + 3];
  Half4* h1p = (Half4*)h1h;
  #pragma unroll
  for (int i = 0; i < 8; ++i) {
    int gn = base + nr * 8 + i;
    float ps = acc[i].x * a10 + acc[i].y * a11 + acc[i].z * a12 + acc[i].w * a13;
    float pd = acc[i].x * a20 + acc[i].y * a21 + acc[i].z * a22 + acc[i].w * a23;
    ps += __shfl_xor(ps, 1); pd += __shfl_xor(pd, 1);
    ps += __shfl_xor(ps, 2); pd += __shfl_xor(pd, 2);
    ps += __shfl_xor(ps, 4); pd += __shfl_xor(pd, 4);
    if (gn < N) {
      Half4 hv;
      hv.lo = __floats2half2_rn(acc[i].x, acc[i].y);
      hv.hi = __floats2half2_rn(acc[i].z, acc[i].w);
      h1p[gn * 32 + c4] = hv;
      if ((c4 & 7) == 0) { als[gn * 4 + hh] = ps; ald[gn * 4 + hh] = pd; }
    }
  }
}

// ---------------- GEMM 2: h2 = h2in(fp16) @ W2, h2 -> fp16 ----------------

__global__ void __launch_bounds__(256) k_gemm2(
    const __half* __restrict__ hin, const float* __restrict__ W,
    const float* __restrict__ as, const float* __restrict__ ad,
    __half* __restrict__ h2h, float* __restrict__ als,
    float* __restrict__ ald, int N) {
  __shared__ float4 xs[64 * XS_STRIDE];   // 33792 B
  __shared__ float2 ws[128 * 16];         // 16384 B : W2 as float2 [128 k][16 colpairs]
  int t = threadIdx.x;
  int base = blockIdx.x * 64;
  const uint2* xg = (const uint2*)hin;
  #pragma unroll
  for (int i = 0; i < 8; ++i) {
    int idx = t + i * 256;
    int n = idx >> 5, k4 = idx & 31;
    int gn = base + n; if (gn >= N) gn = N - 1;
    uint2 u = xg[gn * 32 + k4];
    __half2 a = *(const __half2*)&u.x;
    __half2 b = *(const __half2*)&u.y;
    float2 fa = __half22float2(a), fb = __half22float2(b);
    xs[n * XS_STRIDE + k4] = make_float4(fa.x, fa.y, fb.x, fb.y);
  }
  const float2* w2g = (const float2*)W;
  #pragma unroll
  for (int i = 0; i < 8; ++i) ws[t + i * 256] = w2g[t + i * 256];
  __syncthreads();

  int c2 = t & 15, nr = t >> 4;
  float2 acc[4];
  #pragma unroll
  for (int i = 0; i < 4; ++i) acc[i] = make_float2(0.f, 0.f);

  #pragma unroll 4
  for (int k4 = 0; k4 < 32; ++k4) {
    float2 w0 = ws[(k4 * 4 + 0) * 16 + c2];
    float2 w1 = ws[(k4 * 4 + 1) * 16 + c2];
    float2 w2v = ws[(k4 * 4 + 2) * 16 + c2];
    float2 w3 = ws[(k4 * 4 + 3) * 16 + c2];
    #pragma unroll
    for (int i = 0; i < 4; ++i) {
      float4 xv = xs[(nr * 4 + i) * XS_STRIDE + k4];
      acc[i].x += xv.x * w0.x + xv.y * w1.x + xv.z * w2v.x + xv.w * w3.x;
      acc[i].y += xv.x * w0.y + xv.y * w1.y + xv.z * w2v.y + xv.w * w3.y;
    }
  }

  int hh = c2 >> 2;
  int cl = (c2 & 3) * 2;
  float a10 = as[hh * 8 + cl], a11 = as[hh * 8 + cl + 1];
  float a20 = ad[hh * 8 + cl], a21 = ad[hh * 8 + cl + 1];
  __half2* h2p = (__half2*)h2h;
  #pragma unroll
  for (int i = 0; i < 4; ++i) {
    int gn = base + nr * 4 + i;
    float ps = acc[i].x * a10 + acc[i].y * a11;
    float pd = acc[i].x * a20 + acc[i].y * a21;
    ps += __shfl_xor(ps, 1); pd += __shfl_xor(pd, 1);
    ps += __shfl_xor(ps, 2); pd += __shfl_xor(pd, 2);
    if (gn < N) {
      h2p[gn * 16 + c2] = __floats2half2_rn(acc[i].x, acc[i].y);
      if ((c2 & 3) == 0) { als[gn * 4 + hh] = ps; ald[gn * 4 + hh] = pd; }
    }
  }
}

// ---------------- Aggregation layer 1 (one wave per node, 8-edge unrolled gather) ----------------
// 32 weight lane-slots: (edge jw = lane&7) x (head hw = (lane>>3)&3); lanes 32-63
// duplicate slots 0-31 (harmless). Broadcast w(j, own-head h) from lane h*8+j.

__global__ void k_agg1(const int* __restrict__ degp, const unsigned short* __restrict__ adj,
                       const __half* __restrict__ h1h, const float* __restrict__ als,
                       const float* __restrict__ ald, const float* __restrict__ bias,
                       __half* __restrict__ outh, int N) {
  int wid = (blockIdx.x * blockDim.x + threadIdx.x) >> 6;
  int lane = threadIdx.x & 63;
  if (wid >= N) return;
  int h = lane >> 4;                    // own head (cols 2*lane, 2*lane+1)
  int hb = h * 8;
  int jw = lane & 7, hw = (lane >> 3) & 3;
  float aldw = ald[wid * 4 + hw];       // weight-lane role
  float aldo = ald[wid * 4 + h];        // tail (own head)
  int deg = degp[wid]; if (deg > MAXDEG) deg = MAXDEG;
  const unsigned short* arow = adj + (size_t)wid * MAXDEG;
  float acc0 = 0.f, acc1 = 0.f, wsum = 0.f;
  const __half2* h1v = (const __half2*)h1h;
  int p = 0;
  for (; p + 7 < deg; p += 8) {
    int sj = arow[p + jw];
    int s0 = __shfl(sj, 0), s1 = __shfl(sj, 1), s2 = __shfl(sj, 2), s3 = __shfl(sj, 3);
    int s4 = __shfl(sj, 4), s5 = __shfl(sj, 5), s6 = __shfl(sj, 6), s7 = __shfl(sj, 7);
    float2 v0 = __half22float2(h1v[s0 * 64 + lane]);
    float2 v1 = __half22float2(h1v[s1 * 64 + lane]);
    float2 v2 = __half22float2(h1v[s2 * 64 + lane]);
    float2 v3 = __half22float2(h1v[s3 * 64 + lane]);
    float2 v4 = __half22float2(h1v[s4 * 64 + lane]);
    float2 v5 = __half22float2(h1v[s5 * 64 + lane]);
    float2 v6 = __half22float2(h1v[s6 * 64 + lane]);
    float2 v7 = __half22float2(h1v[s7 * 64 + lane]);
    float ew = als[sj * 4 + hw] + aldw;
    ew = (ew > 0.f) ? ew : 0.2f * ew;
    float w = __expf(ew);
    float w0 = __shfl(w, hb + 0), w1 = __shfl(w, hb + 1),
          w2 = __shfl(w, hb + 2), w3 = __shfl(w, hb + 3),
          w4 = __shfl(w, hb + 4), w5 = __shfl(w, hb + 5),
          w6 = __shfl(w, hb + 6), w7 = __shfl(w, hb + 7);
    wsum += ((w0 + w1) + (w2 + w3)) + ((w4 + w5) + (w6 + w7));
    acc0 += (w0 * v0.x + w1 * v1.x + w2 * v2.x + w3 * v3.x)
          + (w4 * v4.x + w5 * v5.x + w6 * v6.x + w7 * v7.x);
    acc1 += (w0 * v0.y + w1 * v1.y + w2 * v2.y + w3 * v3.y)
          + (w4 * v4.y + w5 * v5.y + w6 * v6.y + w7 * v7.y);
  }
  for (; p < deg; ++p) {
    int s0 = arow[p];
    float e0 = als[s0 * 4 + h] + aldo;
    e0 = (e0 > 0.f) ? e0 : 0.2f * e0;
    float w0 = __expf(e0);
    float2 v0 = __half22float2(h1v[s0 * 64 + lane]);
    wsum += w0;
    acc0 += w0 * v0.x;
    acc1 += w0 * v0.y;
  }
  float inv = 1.f / wsum;
  float o0 = fmaxf(acc0 * inv + bias[lane * 2 + 0], 0.f);
  float o1 = fmaxf(acc1 * inv + bias[lane * 2 + 1], 0.f);
  ((__half2*)outh)[wid * 64 + lane] = __floats2half2_rn(o0, o1);
}

// ---------------- Aggregation layer 2 + bias + log_softmax (32 lanes per node, 8-edge unrolled) ----------------

__global__ void k_agg2(const int* __restrict__ degp, const unsigned short* __restrict__ adj,
                       const __half* __restrict__ h2h, const float* __restrict__ als,
                       const float* __restrict__ ald, const float* __restrict__ bias,
                       float* __restrict__ out, int N) {
  int tid = blockIdx.x * blockDim.x + threadIdx.x;
  int node = tid >> 5;
  int sl = threadIdx.x & 31;
  if (node >= N) return;
  int h = sl >> 3;                       // own head (col sl)
  int hb = h * 8;
  int jw = sl & 7, hw = (sl >> 3) & 3;   // 32 slots exactly: (8 edges) x (4 heads)
  float aldw = ald[node * 4 + hw];
  float aldo = ald[node * 4 + h];
  int deg = degp[node]; if (deg > MAXDEG) deg = MAXDEG;
  const unsigned short* arow = adj + (size_t)node * MAXDEG;
  float acc = 0.f, wsum = 0.f;
  int p = 0;
  for (; p + 7 < deg; p += 8) {
    int sj = arow[p + jw];
    int s0 = __shfl(sj, 0, 32), s1 = __shfl(sj, 1, 32),
        s2 = __shfl(sj, 2, 32), s3 = __shfl(sj, 3, 32),
        s4 = __shfl(sj, 4, 32), s5 = __shfl(sj, 5, 32),
        s6 = __shfl(sj, 6, 32), s7 = __shfl(sj, 7, 32);
    float x0 = __half2float(h2h[s0 * 32 + sl]);
    float x1 = __half2float(h2h[s1 * 32 + sl]);
    float x2 = __half2float(h2h[s2 * 32 + sl]);
    float x3 = __half2float(h2h[s3 * 32 + sl]);
    float x4 = __half2float(h2h[s4 * 32 + sl]);
    float x5 = __half2float(h2h[s5 * 32 + sl]);
    float x6 = __half2float(h2h[s6 * 32 + sl]);
    float x7 = __half2float(h2h[s7 * 32 + sl]);
    float ew = als[sj * 4 + hw] + aldw;
    ew = (ew > 0.f) ? ew : 0.2f * ew;
    float w = __expf(ew);
    float w0 = __shfl(w, hb + 0, 32), w1 = __shfl(w, hb + 1, 32),
          w2 = __shfl(w, hb + 2, 32), w3 = __shfl(w, hb + 3, 32),
          w4 = __shfl(w, hb + 4, 32), w5 = __shfl(w, hb + 5, 32),
          w6 = __shfl(w, hb + 6, 32), w7 = __shfl(w, hb + 7, 32);
    wsum += ((w0 + w1) + (w2 + w3)) + ((w4 + w5) + (w6 + w7));
    acc += ((w0 * x0 + w1 * x1) + (w2 * x2 + w3 * x3))
         + ((w4 * x4 + w5 * x5) + (w6 * x6 + w7 * x7));
  }
  for (; p < deg; ++p) {
    int s0 = arow[p];
    float e0 = als[s0 * 4 + h] + aldo;
    e0 = (e0 > 0.f) ? e0 : 0.2f * e0;
    float w0 = __expf(e0);
    wsum += w0;
    acc += w0 * __half2float(h2h[s0 * 32 + sl]);
  }
  float val = acc / wsum + bias[sl];
  float m = val;
  for (int off = 16; off; off >>= 1) m = fmaxf(m, __shfl_xor(m, off, 32));
  float ex = __expf(val - m);
  float ssum = ex;
  for (int off = 16; off; off >>= 1) ssum += __shfl_xor(ssum, off, 32);
  out[node * 32 + sl] = val - m - __logf(ssum);
}

// ---------------- launch ----------------

extern "C" void kernel_launch(void* const* d_in, const int* in_sizes, int n_in,
                              void* d_out, int out_size, void* d_ws, size_t ws_size,
                              hipStream_t stream) {
  const float* x   = (const float*)d_in[0];
  const int*   ei  = (const int*)d_in[1];
  const float* W1  = (const float*)d_in[2];
  const float* as1 = (const float*)d_in[3];
  const float* ad1 = (const float*)d_in[4];
  const float* b1  = (const float*)d_in[5];
  const float* W2  = (const float*)d_in[6];
  const float* as2 = (const float*)d_in[7];
  const float* ad2 = (const float*)d_in[8];
  const float* b2  = (const float*)d_in[9];
  float* outp = (float*)d_out;

  int N  = in_sizes[0] / 128;   // 50000
  int E  = in_sizes[1] / 2;     // 800000
  int Et = E + N;               // with self loops

  char* wsp = (char*)d_ws;
  size_t off = 0;
  auto alloc = [&](size_t bytes) -> void* {
    void* p = wsp + off;
    off += (bytes + 255) & ~(size_t)255;
    return p;
  };
  int*            cursor = (int*)alloc((size_t)N * 4);
  unsigned short* adj    = (unsigned short*)alloc((size_t)N * MAXDEG * 2);
  __half*         h1     = (__half*)alloc((size_t)N * 128 * 2);
  float*          al1s   = (float*)alloc((size_t)N * 4 * 4);
  float*          al1d   = (float*)alloc((size_t)N * 4 * 4);
  __half*         h2in   = (__half*)alloc((size_t)N * 128 * 2);
  __half*         h2     = (__half*)alloc((size_t)N * 32 * 2);
  float*          al2s   = (float*)alloc((size_t)N * 4 * 4);
  float*          al2d   = (float*)alloc((size_t)N * 4 * 4);

  hipMemsetAsync(cursor, 0, (size_t)N * 4, stream);

  int gb = (N + 63) / 64;        // 782 gemm1 tiles
  int eb = (Et + 255) / 256;     // 3321 fill blocks
  k_fg1<<<gb + eb, 256, 0, stream>>>(ei, E, N, gb, cursor, adj,
                                     x, W1, as1, ad1, h1, al1s, al1d);
  k_agg1 <<<(N + 3) / 4, 256, 0, stream>>>(cursor, adj, h1, al1s, al1d, b1, h2in, N);
  k_gemm2<<<gb, 256, 0, stream>>>(h2in, W2, as2, ad2, h2, al2s, al2d, N);
  k_agg2 <<<(N + 7) / 8, 256, 0, stream>>>(cursor, adj, h2, al2s, al2d, b2, outp, N);
}